// Round 5
// baseline (217.226 us; speedup 1.0000x reference)
//
#include <hip/hip_runtime.h>

typedef __attribute__((ext_vector_type(8))) short short8;
typedef __attribute__((ext_vector_type(4))) float floatx4;

#define MFMA16(a, b, c) __builtin_amdgcn_mfma_f32_16x16x32_bf16((a), (b), (c), 0, 0, 0)

#define LDP 72       // P LDS row stride (ushort): 144B rows, 16B-aligned frags
#define LDOP 264     // Opart row stride (ushort): 528B rows, 16B-aligned frags
#define PSHIFT 23.083120654223414f  // 16*log2(e); Wq pre-scaled by log2(e)

__device__ __forceinline__ float bf2f(unsigned short u) {
  return __uint_as_float(((unsigned int)u) << 16);
}
__device__ __forceinline__ unsigned short f2bf(float f) {
  unsigned int x = __float_as_uint(f);
  x += 0x7FFFu + ((x >> 16) & 1u);   // RNE; finite inputs
  return (unsigned short)(x >> 16);
}
__device__ __forceinline__ float ld_in(const void* p, long i, int isf32) {
  if (isf32) return ((const float*)p)[i];
  return bf2f(((const unsigned short*)p)[i]);
}
__device__ __forceinline__ short8 ld16(const unsigned short* p) {
  return *(const short8*)__builtin_assume_aligned(p, 16);
}
__device__ __forceinline__ void st16(unsigned short* p, short8 v) {
  *(short8*)__builtin_assume_aligned(p, 16) = v;
}

// ---------------------------------------------------------------------------
// Kernel 0: dtype detect, vectorized (R4's scalar loop was latency-bound).
// 64 threads x 8 independent b128 loads = 4096 bf16 samples.
// ---------------------------------------------------------------------------
__global__ void detect_kernel(const unsigned short* __restrict__ in0, int* __restrict__ flag) {
  const int t = threadIdx.x;  // 64
  int bad = 0;
#pragma unroll
  for (int i = 0; i < 8; i++) {
    const short8 v = ld16(in0 + (i * 64 + t) * 8);
#pragma unroll
    for (int j = 0; j < 8; j++) {
      const unsigned int e = (((unsigned short)v[j]) >> 7) & 0xFFu;
      if (e >= 141u) bad = 1;
    }
  }
  unsigned long long m = __ballot(bad);
  if (t == 0) *flag = (m != 0ull) ? 1 : 0;
}

// ---------------------------------------------------------------------------
// Kernel 1: weight prep — coalesced 64x64 LDS-tile transpose (R4 did ~131K
// fully-uncoalesced scalar loads). Wq/bq pre-scaled by log2(e) so flash can
// use native exp2. blk 0..19: Wt_qkv tiles; 20..35: Wt_o tiles; 36: biases.
// ---------------------------------------------------------------------------
__global__ __launch_bounds__(256)
void prep_kernel(const void* __restrict__ Wq, const void* __restrict__ bq,
                 const void* __restrict__ Wk, const void* __restrict__ bk,
                 const void* __restrict__ Wv, const void* __restrict__ bv,
                 const void* __restrict__ Wo, const void* __restrict__ bo,
                 unsigned short* __restrict__ Wt_qkv, unsigned short* __restrict__ Wt_o,
                 float* __restrict__ b_qkv, float* __restrict__ b_o,
                 const int* __restrict__ flag) {
  __shared__ unsigned short Tl[64][72];
  const int isf32 = *flag;
  const int blk = (int)blockIdx.x;
  const int t = (int)threadIdx.x;
  if (blk < 36) {
    const int isO = blk >= 20;
    const int b2 = isO ? blk - 20 : blk;
    const int g0 = (b2 >> 2) * 64, c0 = (b2 & 3) * 64;
    const int j = t & 63, r4 = t >> 6;
#pragma unroll
    for (int k = 0; k < 16; k++) {
      const int rr = r4 * 16 + k;           // src row offset (c), dst col offset
      const int c = c0 + rr, g = g0 + j;
      float v;
      if (isO)         v = ld_in(Wo, (long)c * 256 + g, isf32);
      else if (g < 32) v = ld_in(Wq, (long)c * 32 + g, isf32) * 1.4426950408889634f;
      else if (g < 64) v = ld_in(Wk, (long)c * 32 + (g - 32), isf32);
      else             v = ld_in(Wv, (long)c * 256 + (g - 64), isf32);
      Tl[j][rr] = f2bf(v);                  // T[g_off][c_off]
    }
    __syncthreads();
    unsigned short* dst = isO ? Wt_o : Wt_qkv;
#pragma unroll
    for (int k = 0; k < 16; k++) {
      const int rr = r4 * 16 + k;           // dst row offset (g)
      dst[(long)(g0 + rr) * 256 + c0 + j] = Tl[rr][j];
    }
  } else {
    for (int i = t; i < 320; i += 256) {
      float v = (i < 32) ? ld_in(bq, i, isf32) * 1.4426950408889634f
              : (i < 64) ? ld_in(bk, i - 32, isf32)
                         : ld_in(bv, i - 64, isf32);
      b_qkv[i] = v;
    }
    b_o[t] = ld_in(bo, t, isf32);
  }
}

// ---------------------------------------------------------------------------
// Kernel 2: QKV projection (unchanged from R3/R4 — verified).
// ---------------------------------------------------------------------------
__global__ __launch_bounds__(256)
void proj_kernel(const void* __restrict__ x, const unsigned short* __restrict__ Wt,
                 const float* __restrict__ b_qkv,
                 unsigned short* __restrict__ Q, unsigned short* __restrict__ Kk,
                 unsigned short* __restrict__ Vt, const int* __restrict__ flag) {
  __shared__ unsigned short Vl[64 * LDP];
  const int isf32 = *flag;
  const int t = threadIdx.x;
  const int ct = (int)(blockIdx.x % 5u);
  const long row_base = (long)(blockIdx.x / 5u) * 64;
  const int wave = t >> 6, lane = t & 63, quad = lane >> 4, l15 = lane & 15;
  const long arow = row_base + wave * 16 + l15;

  floatx4 acc[4];
  acc[0] = acc[1] = acc[2] = acc[3] = (floatx4)0.0f;

#pragma unroll
  for (int ks = 0; ks < 8; ks++) {
    short8 a;
    if (isf32) {
      const float* xf = (const float*)x + arow * 256 + ks * 32 + quad * 8;
      floatx4 f0 = *(const floatx4*)xf;
      floatx4 f1 = *(const floatx4*)(xf + 4);
#pragma unroll
      for (int j = 0; j < 4; j++) { a[j] = (short)f2bf(f0[j]); a[4 + j] = (short)f2bf(f1[j]); }
    } else {
      a = ld16((const unsigned short*)x + arow * 256 + ks * 32 + quad * 8);
    }
#pragma unroll
    for (int tn = 0; tn < 4; tn++) {
      const short8 bfr = ld16(Wt + (long)(ct * 64 + tn * 16 + l15) * 256 + ks * 32 + quad * 8);
      acc[tn] = MFMA16(a, bfr, acc[tn]);
    }
  }

  if (ct == 0) {
#pragma unroll
    for (int tn = 0; tn < 4; tn++) {
      const int g = tn * 16 + l15;
      const float bias = b_qkv[g];
#pragma unroll
      for (int r = 0; r < 4; r++) {
        const long row = row_base + wave * 16 + quad * 4 + r;
        const unsigned short h = f2bf(fmaxf(acc[tn][r] + bias, 0.0f));
        if (g < 32) Q[row * 32 + g] = h;
        else        Kk[row * 32 + (g - 32)] = h;
      }
    }
  } else {
#pragma unroll
    for (int tn = 0; tn < 4; tn++) {
      const float bias = b_qkv[ct * 64 + tn * 16 + l15];
#pragma unroll
      for (int r = 0; r < 4; r++)
        Vl[(tn * 16 + l15) * LDP + wave * 16 + quad * 4 + r] =
            f2bf(fmaxf(acc[tn][r] + bias, 0.0f));
    }
    __syncthreads();
    const int chl = t >> 2, nc = (t & 3) * 16;
    const long bb = row_base >> 12, n0 = row_base & 4095;
    unsigned short* dst = Vt + (bb * 256 + (long)(ct - 1) * 64 + chl) * 4096 + n0 + nc;
    st16(dst,     ld16(&Vl[chl * LDP + nc]));
    st16(dst + 8, ld16(&Vl[chl * LDP + nc + 8]));
  }
}

// ---------------------------------------------------------------------------
// Kernel 3: flash attention, DUAL-PIPELINE (split-K in-block) + fused out-proj.
// 256 blocks x 1024 threads (16 waves = 4 waves/SIMD). Pipeline p = wave>>3
// processes keys [2048p, 2048p+2048) with its own double-buffered Pl; the two
// pipelines share barriers but have independent work, so one pipeline's
// barrier-drain stalls are filled by the other's MFMA/VALU (R3/R4 had nothing
// to fill them -> identical 104us).
// Constant-shift softmax => partial O's are additive: combine in LDS at the
// end (Opart overlays dead Pl; normalization folded into epilogue scale).
// ---------------------------------------------------------------------------
__global__ __launch_bounds__(1024, 4)
void flash_kernel(const unsigned short* __restrict__ Q,
                  const unsigned short* __restrict__ K,
                  const unsigned short* __restrict__ Vt,
                  const unsigned short* __restrict__ Wt_o,
                  const float* __restrict__ b_o,
                  const void* __restrict__ xin, void* __restrict__ out,
                  const int* __restrict__ flag) {
  __shared__ unsigned short Pl[2][2][64 * LDP];   // 36.9 KB [pipe][buf]
  __shared__ float Lp[2][2][64];                  // [pipe][colhalf][row]
  __shared__ float Ll[64];
  unsigned short* const Opart = &Pl[0][0][0];     // overlay: 64*LDOP <= Pl size

  const int t = threadIdx.x;
  const int raw = (int)blockIdx.x;
  const int x8 = raw & 7;
  const int b = x8 & 3;                           // batch -> XCD pair {b, b+4}
  const int mt = (raw >> 3) | ((x8 >> 2) << 5);
  const long qrow0 = (long)b * 4096 + (long)mt * 64;
  const int wave = t >> 6, lane = t & 63, quad = lane >> 4, l15 = lane & 15;
  const int pipe = wave >> 3, w8 = wave & 7;
  const int m = w8 & 3, h = w8 >> 2;              // S rows [16m,16m+16), cols [32h,32h+32)

  const unsigned short* kbase = K + ((long)b * 4096 + pipe * 2048) * 32;
  const unsigned short* vbase = Vt + ((long)b * 256 + w8 * 32 + l15) * 4096 + pipe * 2048;

  const short8 qf = ld16(Q + (qrow0 + m * 16 + l15) * 32 + quad * 8);
  short8 kb[2];
#pragma unroll
  for (int i = 0; i < 2; i++)
    kb[i] = ld16(kbase + (long)((h * 2 + i) * 16 + l15) * 32 + quad * 8);
  short8 vb[2][2];
#pragma unroll
  for (int tv = 0; tv < 2; tv++)
#pragma unroll
    for (int kh = 0; kh < 2; kh++)
      vb[tv][kh] = ld16(vbase + (long)tv * 16 * 4096 + kh * 32 + quad * 8);

  floatx4 oacc[4][2];
#pragma unroll
  for (int i = 0; i < 4; i++) { oacc[i][0] = (floatx4)0.0f; oacc[i][1] = (floatx4)0.0f; }
  float lpart[4] = {0.0f, 0.0f, 0.0f, 0.0f};

  for (int kt = 0; kt < 32; kt++) {
    floatx4 s[2];
#pragma unroll
    for (int i = 0; i < 2; i++) { s[i] = (floatx4)0.0f; s[i] = MFMA16(qf, kb[i], s[i]); }
    const int ktn = (kt + 1) & 31;
#pragma unroll
    for (int i = 0; i < 2; i++)
      kb[i] = ld16(kbase + (long)(ktn * 64 + (h * 2 + i) * 16 + l15) * 32 + quad * 8);

    unsigned short* pl = Pl[pipe][kt & 1];
#pragma unroll
    for (int i = 0; i < 2; i++)
#pragma unroll
      for (int r = 0; r < 4; r++) {
        const float p = exp2f(s[i][r] - PSHIFT);   // = exp(s_orig - 16)
        lpart[r] += p;
        pl[(m * 16 + quad * 4 + r) * LDP + (h * 2 + i) * 16 + l15] = f2bf(p);
      }
    __syncthreads();   // publish P(kt) for this pipe (both pipes in lockstep)

    short8 vbn[2][2];
#pragma unroll
    for (int tv = 0; tv < 2; tv++)
#pragma unroll
      for (int kh = 0; kh < 2; kh++)
        vbn[tv][kh] = ld16(vbase + (long)tv * 16 * 4096 + ktn * 64 + kh * 32 + quad * 8);

    const unsigned short* plr = Pl[pipe][kt & 1];
    short8 pa[4][2];
#pragma unroll
    for (int mm = 0; mm < 4; mm++)
#pragma unroll
      for (int kh = 0; kh < 2; kh++)
        pa[mm][kh] = ld16(&plr[(mm * 16 + l15) * LDP + kh * 32 + quad * 8]);

#pragma unroll
    for (int kh = 0; kh < 2; kh++)
#pragma unroll
      for (int tv = 0; tv < 2; tv++)
#pragma unroll
        for (int mm = 0; mm < 4; mm++)
          oacc[mm][tv] = MFMA16(pa[mm][kh], vb[tv][kh], oacc[mm][tv]);

#pragma unroll
    for (int tv = 0; tv < 2; tv++)
#pragma unroll
      for (int kh = 0; kh < 2; kh++)
        vb[tv][kh] = vbn[tv][kh];
  }

  // per-wave l partial (rows m*16.., cols [32h,32h+32)) -> Lp
#pragma unroll
  for (int r = 0; r < 4; r++)
#pragma unroll
    for (int off = 1; off < 16; off <<= 1)
      lpart[r] += __shfl_xor(lpart[r], off);
  if (l15 == 0) {
    floatx4 lw;
#pragma unroll
    for (int r = 0; r < 4; r++) lw[r] = lpart[r];
    *(floatx4*)&Lp[pipe][h][m * 16 + quad * 4] = lw;
  }
  __syncthreads();   // #33: all Pl reads done (Opart may now overlay), Lp visible

  if (pipe == 1) {   // publish pipe-1 partial O (unnormalized, bf16)
#pragma unroll
    for (int mm = 0; mm < 4; mm++)
#pragma unroll
      for (int tv = 0; tv < 2; tv++)
#pragma unroll
        for (int r = 0; r < 4; r++)
          Opart[(mm * 16 + quad * 4 + r) * LDOP + w8 * 32 + tv * 16 + l15] =
              f2bf(oacc[mm][tv][r]);
  }
  __syncthreads();   // #34: Opart visible
  if (t < 64) Ll[t] = 1.0f / (Lp[0][0][t] + Lp[0][1][t] + Lp[1][0][t] + Lp[1][1][t]);
  __syncthreads();   // #35: Ll visible
  if (pipe == 0) {   // combine in place (each lane owns its addresses)
#pragma unroll
    for (int mm = 0; mm < 4; mm++)
#pragma unroll
      for (int tv = 0; tv < 2; tv++)
#pragma unroll
        for (int r = 0; r < 4; r++) {
          const int idx = (mm * 16 + quad * 4 + r) * LDOP + w8 * 32 + tv * 16 + l15;
          Opart[idx] = f2bf(bf2f(Opart[idx]) + oacc[mm][tv][r]);
        }
  }
  __syncthreads();   // #36: combined O ready

  // ---- fused out-projection; row-normalization folded into output scale ----
  const int m2 = wave & 3, gh = wave >> 2;        // 16 waves: 4 row x 4 col groups
  floatx4 acc2[4];
#pragma unroll
  for (int i = 0; i < 4; i++) acc2[i] = (floatx4)0.0f;
#pragma unroll
  for (int ks = 0; ks < 8; ks++) {
    const short8 a = ld16((const unsigned short*)__builtin_assume_aligned(
        &Opart[(m2 * 16 + l15) * LDOP + ks * 32 + quad * 8], 16));
#pragma unroll
    for (int tn = 0; tn < 4; tn++) {
      const short8 bfr = ld16(Wt_o + (long)(gh * 64 + tn * 16 + l15) * 256 + ks * 32 + quad * 8);
      acc2[tn] = MFMA16(a, bfr, acc2[tn]);
    }
  }
  const int isf32 = *flag;
  const floatx4 ll = *(const floatx4*)&Ll[m2 * 16 + quad * 4];
#pragma unroll
  for (int tn = 0; tn < 4; tn++) {
    const int g = gh * 64 + tn * 16 + l15;
    const float bias = b_o[g];
#pragma unroll
    for (int r = 0; r < 4; r++) {
      const long row = qrow0 + m2 * 16 + quad * 4 + r;
      const long gi = row * 256 + g;
      const float vv = fmaxf(acc2[tn][r] * ll[r] + bias, 0.0f) + ld_in(xin, gi, isf32);
      if (isf32) ((float*)out)[gi] = vv;
      else       ((unsigned short*)out)[gi] = f2bf(vv);
    }
  }
}

extern "C" void kernel_launch(void* const* d_in, const int* in_sizes, int n_in,
                              void* d_out, int out_size, void* d_ws, size_t ws_size,
                              hipStream_t stream) {
  const void* x  = d_in[0];
  const void* Wq = d_in[1]; const void* bq = d_in[2];
  const void* Wk = d_in[3]; const void* bk = d_in[4];
  const void* Wv = d_in[5]; const void* bv = d_in[6];
  const void* Wo = d_in[7]; const void* bo = d_in[8];

  char* ws = (char*)d_ws;
  int*            flag   = (int*)ws;
  unsigned short* Wt_qkv = (unsigned short*)(ws + 256);
  unsigned short* Wt_o   = (unsigned short*)(ws + 164096);
  float*          b_qkv  = (float*)(ws + 295168);
  float*          b_o    = (float*)(ws + 296448);
  unsigned short* Q      = (unsigned short*)(ws + 297472);
  unsigned short* K      = Q + (long)4 * 4096 * 32;
  unsigned short* Vt     = K + (long)4 * 4096 * 32;

  detect_kernel<<<1, 64, 0, stream>>>((const unsigned short*)x, flag);
  prep_kernel<<<37, 256, 0, stream>>>(Wq, bq, Wk, bk, Wv, bv, Wo, bo,
                                      Wt_qkv, Wt_o, b_qkv, b_o, flag);
  proj_kernel<<<1280, 256, 0, stream>>>(x, Wt_qkv, b_qkv, Q, K, Vt, flag);
  flash_kernel<<<256, 1024, 0, stream>>>(Q, K, Vt, Wt_o, b_o, x, d_out, flag);
}